// Round 1
// baseline (472.323 us; speedup 1.0000x reference)
//
#include <hip/hip_runtime.h>
#include <hip/hip_bf16.h>

#define HEADS  16
#define DIMH   64
#define NBATCH 2
#define SEQ    2048
#define DMODEL 1024
#define MROWS  (NBATCH * SEQ)   // 4096

typedef __attribute__((ext_vector_type(8))) short bf16x8;
typedef __attribute__((ext_vector_type(4))) float f32x4;
typedef __attribute__((ext_vector_type(4))) float float4v;
typedef __attribute__((ext_vector_type(4))) short short4v;

// ---------------- f32 -> bf16 cast (4 elems/thread) ----------------
__global__ void cvt_kernel(const float* __restrict__ in,
                           __hip_bfloat16* __restrict__ out, int n4) {
    int i = blockIdx.x * blockDim.x + threadIdx.x;
    if (i >= n4) return;
    float4v v = reinterpret_cast<const float4v*>(in)[i];
    union { short4v s; __hip_bfloat16 h[4]; } u;
#pragma unroll
    for (int j = 0; j < 4; ++j) u.h[j] = __float2bfloat16(v[j]);
    reinterpret_cast<short4v*>(out)[i] = u.s;
}

// ------------- W [D][D] f32 -> WT [o][i] bf16 (transpose+cast) -------------
__global__ void tr_kernel(const float* __restrict__ W,
                          __hip_bfloat16* __restrict__ WT) {
    __shared__ float tile[32][33];
    int i = blockIdx.y * 32 + threadIdx.y;   // row of W
    int o = blockIdx.x * 32 + threadIdx.x;   // col of W
    tile[threadIdx.y][threadIdx.x] = W[i * DMODEL + o];
    __syncthreads();
    int oo = blockIdx.x * 32 + threadIdx.y;  // row of WT
    int ii = blockIdx.y * 32 + threadIdx.x;  // col of WT
    WT[oo * DMODEL + ii] = __float2bfloat16(tile[threadIdx.x][threadIdx.y]);
}

// ---------------- fused Q/KV projection GEMM ----------------
// hsb [4096][1024] bf16, WqT/WkvT [out][in] bf16.
// Writes q [B,H,S,Dh], k [B,H,S,Dh], vt [B,H,Dh,S]  (v == k).
__launch_bounds__(256)
__global__ void proj_kernel(const __hip_bfloat16* __restrict__ hsb,
                            const __hip_bfloat16* __restrict__ WqT,
                            const __hip_bfloat16* __restrict__ WkvT,
                            __hip_bfloat16* __restrict__ qb,
                            __hip_bfloat16* __restrict__ kb,
                            __hip_bfloat16* __restrict__ vtb) {
    const int lane = threadIdx.x & 63;
    const int wave = threadIdx.x >> 6;
    const int lr = lane & 15;
    const int lk = lane >> 4;
    const int mbase = blockIdx.y * 64 + wave * 16;
    const int nb = blockIdx.x * 64;            // 0..2047 (q half then kv half)
    const bool is_q = nb < DMODEL;
    const __hip_bfloat16* __restrict__ WT = is_q ? WqT : WkvT;
    const int nbase = is_q ? nb : nb - DMODEL;

    f32x4 acc[4] = {};
    for (int k0 = 0; k0 < DMODEL; k0 += 32) {
        bf16x8 a = *reinterpret_cast<const bf16x8*>(
            &hsb[(size_t)(mbase + lr) * DMODEL + k0 + lk * 8]);
#pragma unroll
        for (int nt = 0; nt < 4; ++nt) {
            bf16x8 b = *reinterpret_cast<const bf16x8*>(
                &WT[(size_t)(nbase + nt * 16 + lr) * DMODEL + k0 + lk * 8]);
            acc[nt] = __builtin_amdgcn_mfma_f32_16x16x32_bf16(a, b, acc[nt], 0, 0, 0);
        }
    }
    // C layout: col = lane&15, row = (lane>>4)*4 + r
#pragma unroll
    for (int nt = 0; nt < 4; ++nt) {
#pragma unroll
        for (int r = 0; r < 4; ++r) {
            int m = mbase + lk * 4 + r;          // 0..4095
            int b_ = m >> 11, s = m & (SEQ - 1);
            int n = nbase + nt * 16 + lr;        // 0..1023
            int h = n >> 6, dh = n & 63;
            __hip_bfloat16 hv = __float2bfloat16(acc[nt][r]);
            size_t idx = ((size_t)(b_ * HEADS + h) * SEQ + s) * DIMH + dh;
            if (is_q) {
                qb[idx] = hv;
            } else {
                kb[idx] = hv;
                vtb[((size_t)(b_ * HEADS + h) * DIMH + dh) * SEQ + s] = hv;
            }
        }
    }
}

// ---------------- fused ReLU attention ----------------
// grid: B*H*(S/64) blocks, 4 waves each; wave owns 16 q-rows, no barriers.
__launch_bounds__(256)
__global__ void attn_kernel(const __hip_bfloat16* __restrict__ qb,
                            const __hip_bfloat16* __restrict__ kb,
                            const __hip_bfloat16* __restrict__ vtb,
                            __hip_bfloat16* __restrict__ ao) {
    __shared__ __align__(16) unsigned char Plds[4][16 * 128]; // per-wave P tile [16q][64t] bf16, XOR-swizzled
    const int lane = threadIdx.x & 63;
    const int wave = threadIdx.x >> 6;
    const int lr = lane & 15;
    const int lk = lane >> 4;
    const int bh = blockIdx.x >> 5;            // 0..31  (= b*16 + h)
    const int qblk = blockIdx.x & 31;
    const int b_ = bh >> 4, h = bh & 15;
    const int qbase = qblk * 64 + wave * 16;   // s-offset of this wave's q tile

    const __hip_bfloat16* __restrict__ Q = qb + (size_t)bh * SEQ * DIMH;
    const __hip_bfloat16* __restrict__ K = kb + (size_t)bh * SEQ * DIMH;
    const __hip_bfloat16* __restrict__ VT = vtb + (size_t)bh * DIMH * SEQ;
    unsigned char* P = Plds[wave];

    // Q fragments for this wave's 16 rows (Dh=64 -> 2 k-steps), loaded once
    bf16x8 qf[2];
#pragma unroll
    for (int ks = 0; ks < 2; ++ks)
        qf[ks] = *reinterpret_cast<const bf16x8*>(
            &Q[(size_t)(qbase + lr) * DIMH + ks * 32 + lk * 8]);

    f32x4 acco[4] = {};
    const float scale = 0.125f;   // 1/sqrt(64)

    for (int t0 = 0; t0 < SEQ; t0 += 64) {
        // ---- S = Q K^T over a 16q x 64t tile ----
        f32x4 sacc[4] = {};
#pragma unroll
        for (int nt = 0; nt < 4; ++nt) {
#pragma unroll
            for (int ks = 0; ks < 2; ++ks) {
                bf16x8 kf = *reinterpret_cast<const bf16x8*>(
                    &K[(size_t)(t0 + nt * 16 + lr) * DIMH + ks * 32 + lk * 8]);
                sacc[nt] = __builtin_amdgcn_mfma_f32_16x16x32_bf16(qf[ks], kf, sacc[nt], 0, 0, 0);
            }
        }
        // ---- relu(scale*S) -> bf16 -> LDS (A-fragment layout, swizzled) ----
#pragma unroll
        for (int nt = 0; nt < 4; ++nt) {
#pragma unroll
            for (int r = 0; r < 4; ++r) {
                float v = sacc[nt][r] * scale;
                v = v > 0.f ? v : 0.f;
                int row = lk * 4 + r;
                int bytecol = (nt * 16 + lr) * 2;
                *reinterpret_cast<__hip_bfloat16*>(
                    &P[row * 128 + (bytecol ^ ((row & 7) << 4))]) = __float2bfloat16(v);
            }
        }
        // ---- O += P @ V ----
#pragma unroll
        for (int ks = 0; ks < 2; ++ks) {
            int bytecol = ks * 64 + lk * 16;
            bf16x8 pa = *reinterpret_cast<const bf16x8*>(
                &P[lr * 128 + (bytecol ^ ((lr & 7) << 4))]);
#pragma unroll
            for (int nt = 0; nt < 4; ++nt) {
                bf16x8 vb = *reinterpret_cast<const bf16x8*>(
                    &VT[(size_t)(nt * 16 + lr) * SEQ + t0 + ks * 32 + lk * 8]);
                acco[nt] = __builtin_amdgcn_mfma_f32_16x16x32_bf16(pa, vb, acco[nt], 0, 0, 0);
            }
        }
    }
    // ---- epilogue: ao [B*S][D] bf16, col = h*64 + dh ----
#pragma unroll
    for (int nt = 0; nt < 4; ++nt) {
#pragma unroll
        for (int r = 0; r < 4; ++r) {
            int s = qbase + lk * 4 + r;
            int col = h * 64 + nt * 16 + lr;
            ao[(size_t)(b_ * SEQ + s) * DMODEL + col] = __float2bfloat16(acco[nt][r]);
        }
    }
}

// ---------------- output projection GEMM + bias (f32 out) ----------------
__launch_bounds__(256)
__global__ void outproj_kernel(const __hip_bfloat16* __restrict__ ao,
                               const __hip_bfloat16* __restrict__ WoT,
                               const float* __restrict__ bout,
                               float* __restrict__ out) {
    const int lane = threadIdx.x & 63;
    const int wave = threadIdx.x >> 6;
    const int lr = lane & 15;
    const int lk = lane >> 4;
    const int mbase = blockIdx.y * 64 + wave * 16;
    const int nbase = blockIdx.x * 64;

    f32x4 acc[4] = {};
    for (int k0 = 0; k0 < DMODEL; k0 += 32) {
        bf16x8 a = *reinterpret_cast<const bf16x8*>(
            &ao[(size_t)(mbase + lr) * DMODEL + k0 + lk * 8]);
#pragma unroll
        for (int nt = 0; nt < 4; ++nt) {
            bf16x8 b = *reinterpret_cast<const bf16x8*>(
                &WoT[(size_t)(nbase + nt * 16 + lr) * DMODEL + k0 + lk * 8]);
            acc[nt] = __builtin_amdgcn_mfma_f32_16x16x32_bf16(a, b, acc[nt], 0, 0, 0);
        }
    }
#pragma unroll
    for (int nt = 0; nt < 4; ++nt) {
        float bias = bout[nbase + nt * 16 + lr];
#pragma unroll
        for (int r = 0; r < 4; ++r) {
            int m = mbase + lk * 4 + r;
            out[(size_t)m * DMODEL + nbase + nt * 16 + lr] = acc[nt][r] + bias;
        }
    }
}

extern "C" void kernel_launch(void* const* d_in, const int* in_sizes, int n_in,
                              void* d_out, int out_size, void* d_ws, size_t ws_size,
                              hipStream_t stream) {
    const float* hs   = (const float*)d_in[0];
    const float* Wq   = (const float*)d_in[1];
    const float* Wkv  = (const float*)d_in[2];
    const float* Wout = (const float*)d_in[3];
    const float* bout = (const float*)d_in[4];
    float* out = (float*)d_out;

    char* ws = (char*)d_ws;
    size_t off = 0;
    auto alloc = [&](size_t bytes) { char* p = ws + off; off += bytes; return p; };
    __hip_bfloat16* hsb  = (__hip_bfloat16*)alloc((size_t)MROWS * DMODEL * 2); // 8MB (dead after proj)
    __hip_bfloat16* WqT  = (__hip_bfloat16*)alloc((size_t)DMODEL * DMODEL * 2);
    __hip_bfloat16* WkvT = (__hip_bfloat16*)alloc((size_t)DMODEL * DMODEL * 2);
    __hip_bfloat16* WoT  = (__hip_bfloat16*)alloc((size_t)DMODEL * DMODEL * 2);
    __hip_bfloat16* qb   = (__hip_bfloat16*)alloc((size_t)MROWS * DMODEL * 2);
    __hip_bfloat16* kb   = (__hip_bfloat16*)alloc((size_t)MROWS * DMODEL * 2);
    __hip_bfloat16* vtb  = (__hip_bfloat16*)alloc((size_t)MROWS * DMODEL * 2);
    __hip_bfloat16* ao   = hsb;  // alias: hs_bf16 is dead once attention runs

    // 1. casts / transposes
    cvt_kernel<<<(MROWS * DMODEL / 4 + 255) / 256, 256, 0, stream>>>(hs, hsb, MROWS * DMODEL / 4);
    dim3 trg(32, 32), trb(32, 32);
    tr_kernel<<<trg, trb, 0, stream>>>(Wq, WqT);
    tr_kernel<<<trg, trb, 0, stream>>>(Wkv, WkvT);
    tr_kernel<<<trg, trb, 0, stream>>>(Wout, WoT);

    // 2. fused Q/KV projection
    proj_kernel<<<dim3(2 * DMODEL / 64, MROWS / 64), 256, 0, stream>>>(hsb, WqT, WkvT, qb, kb, vtb);

    // 3. fused relu attention
    attn_kernel<<<NBATCH * HEADS * (SEQ / 64), 256, 0, stream>>>(qb, kb, vtb, ao);

    // 4. output projection
    outproj_kernel<<<dim3(DMODEL / 64, MROWS / 64), 256, 0, stream>>>(ao, WoT, bout, out);
}